// Round 6
// baseline (763.491 us; speedup 1.0000x reference)
//
#include <hip/hip_runtime.h>

#define NUSERS 100000
#define NITEMS 50000
#define NTOT   150000
#define NEDGE  1000000

typedef unsigned int uint32;

__device__ __forceinline__ unsigned short f2bf(float f) {
  unsigned int u = __float_as_uint(f);
  u += 0x7FFFu + ((u >> 16) & 1u);   // round-to-nearest-even
  return (unsigned short)(u >> 16);
}
__device__ __forceinline__ uint32 pack2bf(float a, float b) {
  return (uint32)f2bf(a) | ((uint32)f2bf(b) << 16);
}

// ---- init: emb = concat(user, item); out = emb (embeds_lst[0]) ----
__global__ void k_init(const float* __restrict__ ue, const float* __restrict__ ie,
                       float* __restrict__ emb, float* __restrict__ out) {
  int i = blockIdx.x * 256 + threadIdx.x;  // float4 index
  if (i >= NTOT * 16) return;
  float4 v = (i < NUSERS * 16) ? ((const float4*)ue)[i]
                               : ((const float4*)ie)[i - NUSERS * 16];
  ((float4*)emb)[i] = v;
  ((float4*)out)[i] = v;
}

// ---- CSR build: histogram -> scan -> fill ----
__global__ void k_hist(const int* __restrict__ rows, int* __restrict__ cnt) {
  int e = blockIdx.x * 256 + threadIdx.x;
  if (e < NEDGE) atomicAdd(&cnt[rows[e]], 1);
}

__global__ void k_scan1(const int* __restrict__ cnt, int* __restrict__ partial,
                        int* __restrict__ blocksums) {
  __shared__ int s[256];
  int t = threadIdx.x, b = blockIdx.x;
  int base = b * 2048 + t * 8;
  int pre[8]; int sum = 0;
  #pragma unroll
  for (int j = 0; j < 8; ++j) {
    int idx = base + j;
    int x = (idx < NTOT) ? cnt[idx] : 0;
    pre[j] = sum; sum += x;
  }
  s[t] = sum; __syncthreads();
  for (int off = 1; off < 256; off <<= 1) {
    int x = (t >= off) ? s[t - off] : 0;
    __syncthreads(); s[t] += x; __syncthreads();
  }
  int excl = s[t] - sum;
  #pragma unroll
  for (int j = 0; j < 8; ++j) {
    int idx = base + j;
    if (idx < NTOT) partial[idx] = excl + pre[j];
  }
  if (t == 255) blocksums[b] = s[255];
}

__global__ void k_scan2(const int* __restrict__ blocksums, int* __restrict__ blockoffs, int nblk) {
  __shared__ int s[128];
  int t = threadIdx.x;
  int x = (t < nblk) ? blocksums[t] : 0;
  s[t] = x; __syncthreads();
  for (int off = 1; off < 128; off <<= 1) {
    int y = (t >= off) ? s[t - off] : 0;
    __syncthreads(); s[t] += y; __syncthreads();
  }
  if (t < nblk) blockoffs[t] = s[t] - x;
}

__global__ void k_scan3(int* __restrict__ row_ptr, const int* __restrict__ blockoffs,
                        int* __restrict__ cursor) {
  int i = blockIdx.x * 256 + threadIdx.x;
  if (i < NTOT) {
    int v = row_ptr[i] + blockoffs[i >> 11];
    row_ptr[i] = v; cursor[i] = v;
  }
  if (i == 0) row_ptr[NTOT] = NEDGE;
}

__global__ void k_fill(const int* __restrict__ rows, const int* __restrict__ cols,
                       const float* __restrict__ vals, int* __restrict__ cursor,
                       int* __restrict__ ecols, float* __restrict__ evals) {
  int e = blockIdx.x * 256 + threadIdx.x;
  if (e >= NEDGE) return;
  int r = rows[e];
  int pos = atomicAdd(&cursor[r], 1);
  ecols[pos] = cols[e];
  evals[pos] = vals[e];
}

// ---- QKV projection v4: scalar (s_load) emb reads, weights-only LDS ----
// Block = 256 = 4 waves; wave handles 16 nodes. Node index is wave-uniform
// (readfirstlane) so emb row-chunk loads become s_load_dwordx4 via K$.
// Q fp32 (lane = dim). K/V packed bf16 into KVb as in R5:
// lanes 0-31 own K dim-pairs (2m,2m+1); lanes 32-63 own V dim-pairs.
__global__ void __launch_bounds__(256) k_qkv(const float* __restrict__ emb,
    const float* __restrict__ Wq, const float* __restrict__ Wk, const float* __restrict__ Wv,
    float* __restrict__ Q, uint32* __restrict__ KVb) {
  __shared__ float wq[4096], wk[4096], wv[4096];
  int t = threadIdx.x;
  for (int i = t; i < 4096; i += 256) { wq[i] = Wq[i]; wk[i] = Wk[i]; wv[i] = Wv[i]; }
  __syncthreads();
  int lane = t & 63;
  int wave = __builtin_amdgcn_readfirstlane(t >> 6);
  int nbase = blockIdx.x * 64 + wave * 16;
  int half = lane >> 5;            // 0 -> K, 1 -> V
  int m = lane & 31;               // dim pair (2m, 2m+1)
  const float* wkv = half ? wv : wk;
  float qa[16], kv0[16], kv1[16];
  #pragma unroll
  for (int u = 0; u < 16; ++u) { qa[u] = 0.f; kv0[u] = 0.f; kv1[u] = 0.f; }
  for (int k0 = 0; k0 < 64; k0 += 4) {
    float q0 = wq[(k0 + 0) * 64 + lane], q1 = wq[(k0 + 1) * 64 + lane];
    float q2 = wq[(k0 + 2) * 64 + lane], q3 = wq[(k0 + 3) * 64 + lane];
    float2 w0 = *(const float2*)&wkv[(k0 + 0) * 64 + 2 * m];
    float2 w1 = *(const float2*)&wkv[(k0 + 1) * 64 + 2 * m];
    float2 w2 = *(const float2*)&wkv[(k0 + 2) * 64 + 2 * m];
    float2 w3 = *(const float2*)&wkv[(k0 + 3) * 64 + 2 * m];
    #pragma unroll
    for (int u = 0; u < 16; ++u) {
      int node = nbase + u;
      node = node < NTOT ? node : NTOT - 1;   // uniform clamp (stays scalar)
      float4 e4 = *(const float4*)&emb[node * 64 + k0];  // s_load_dwordx4
      qa[u] = fmaf(e4.x, q0, qa[u]);
      qa[u] = fmaf(e4.y, q1, qa[u]);
      qa[u] = fmaf(e4.z, q2, qa[u]);
      qa[u] = fmaf(e4.w, q3, qa[u]);
      kv0[u] = fmaf(e4.x, w0.x, kv0[u]);
      kv0[u] = fmaf(e4.y, w1.x, kv0[u]);
      kv0[u] = fmaf(e4.z, w2.x, kv0[u]);
      kv0[u] = fmaf(e4.w, w3.x, kv0[u]);
      kv1[u] = fmaf(e4.x, w0.y, kv1[u]);
      kv1[u] = fmaf(e4.y, w1.y, kv1[u]);
      kv1[u] = fmaf(e4.z, w2.y, kv1[u]);
      kv1[u] = fmaf(e4.w, w3.y, kv1[u]);
    }
  }
  int uidx = (m >> 1) * 4 + half * 2 + (m & 1);
  #pragma unroll
  for (int u = 0; u < 16; ++u) {
    int n = nbase + u;
    if (n < NTOT) {
      Q[n * 64 + lane] = qa[u];
      KVb[n * 64 + uidx] = pack2bf(kv0[u], kv1[u]);
    }
  }
}

// ---- GT layer: wave = node; 4 edge-slots x 16 lanes; one dwordx4/edge ----
// Writes emb_out fp32 (read densely by next k_qkv) and embb_out bf16 pairs
// (gathered by GCN layers).
__global__ void __launch_bounds__(256) k_gt(const float* __restrict__ Q,
    const uint32* __restrict__ KVb, const int* __restrict__ row_ptr,
    const int* __restrict__ ecols, float* __restrict__ emb_out,
    uint32* __restrict__ embb_out, float* __restrict__ acc_out) {
  int t = threadIdx.x;
  int n = blockIdx.x * 4 + (t >> 6);
  if (n >= NTOT) return;
  int lane = t & 63;
  int es = lane >> 4;
  int dl = lane & 15;
  float4 q4 = *(const float4*)&Q[n * 64 + dl * 4];
  int s     = __builtin_amdgcn_readfirstlane(row_ptr[n]);
  int e_end = __builtin_amdgcn_readfirstlane(row_ptr[n + 1]);
  float den = 0.f;
  float4 acc = make_float4(0.f, 0.f, 0.f, 0.f);
  #pragma unroll 2
  for (int p = s; p < e_end; p += 4) {
    int idx = p + es;
    float ex = 0.f;
    float4 v4 = make_float4(0.f, 0.f, 0.f, 0.f);
    if (idx < e_end) {
      int c = ecols[idx];
      uint4 w = *(const uint4*)&KVb[c * 64 + dl * 4];
      float kx = __uint_as_float(w.x << 16);
      float ky = __uint_as_float(w.x & 0xFFFF0000u);
      float kz = __uint_as_float(w.y << 16);
      float kw = __uint_as_float(w.y & 0xFFFF0000u);
      v4.x = __uint_as_float(w.z << 16);
      v4.y = __uint_as_float(w.z & 0xFFFF0000u);
      v4.z = __uint_as_float(w.w << 16);
      v4.w = __uint_as_float(w.w & 0xFFFF0000u);
      float x = q4.x * kx + q4.y * ky + q4.z * kz + q4.w * kw;
      x += __shfl_xor(x, 1);
      x += __shfl_xor(x, 2);
      x = fminf(fmaxf(x, -10.f), 10.f);
      ex = __expf(x);
    }
    den += ex;
    acc.x = fmaf(ex, v4.x, acc.x);
    acc.y = fmaf(ex, v4.y, acc.y);
    acc.z = fmaf(ex, v4.z, acc.z);
    acc.w = fmaf(ex, v4.w, acc.w);
  }
  // reduce across the 4 edge slots
  #pragma unroll
  for (int off = 16; off <= 32; off <<= 1) {
    den  += __shfl_xor(den, off);
    acc.x += __shfl_xor(acc.x, off);
    acc.y += __shfl_xor(acc.y, off);
    acc.z += __shfl_xor(acc.z, off);
    acc.w += __shfl_xor(acc.w, off);
  }
  float inv = 1.f / (den + 1e-8f);
  float4 r = make_float4(acc.x * inv, acc.y * inv, acc.z * inv, acc.w * inv);
  if (es == 0) {
    *(float4*)&emb_out[n * 64 + dl * 4] = r;
  } else if (es == 1) {
    float4 o = *(const float4*)&acc_out[n * 64 + dl * 4];
    o.x += r.x; o.y += r.y; o.z += r.z; o.w += r.w;
    *(float4*)&acc_out[n * 64 + dl * 4] = o;
  } else if (es == 2) {
    uint2 pk;
    pk.x = pack2bf(r.x, r.y);
    pk.y = pack2bf(r.z, r.w);
    *(uint2*)&embb_out[n * 32 + dl * 2] = pk;
  }
}

// ---- GCN layer v4 (spmm): bf16 gather; 2 edge-slots x 32 lanes x uint ----
// es2 = lane>>5 (edge slot), dl = lane&31 (dims 2dl, 2dl+1). 128 B/edge.
// Writes bf16 out (for next GCN gather) + acc only; fp32 out never read.
__global__ void __launch_bounds__(256) k_gcn(const uint32* __restrict__ embb,
    const int* __restrict__ row_ptr, const int* __restrict__ ecols, const float* __restrict__ evals,
    uint32* __restrict__ embb_out, float* __restrict__ acc_out) {
  int t = threadIdx.x;
  int n = blockIdx.x * 4 + (t >> 6);
  if (n >= NTOT) return;
  int lane = t & 63;
  int es2 = lane >> 5;
  int dl = lane & 31;
  int s     = __builtin_amdgcn_readfirstlane(row_ptr[n]);
  int e_end = __builtin_amdgcn_readfirstlane(row_ptr[n + 1]);
  float a0 = 0.f, a1 = 0.f, b0 = 0.f, b1 = 0.f;
  for (int p = s; p < e_end; p += 4) {
    int i0 = p + es2;
    int i1 = p + 2 + es2;
    if (i0 < e_end) {
      int c = ecols[i0];
      float w = evals[i0];
      uint32 u = embb[c * 32 + dl];
      a0 = fmaf(w, __uint_as_float(u << 16), a0);
      a1 = fmaf(w, __uint_as_float(u & 0xFFFF0000u), a1);
    }
    if (i1 < e_end) {
      int c = ecols[i1];
      float w = evals[i1];
      uint32 u = embb[c * 32 + dl];
      b0 = fmaf(w, __uint_as_float(u << 16), b0);
      b1 = fmaf(w, __uint_as_float(u & 0xFFFF0000u), b1);
    }
  }
  a0 += b0; a1 += b1;
  a0 += __shfl_xor(a0, 32);
  a1 += __shfl_xor(a1, 32);
  if (es2 == 0) {
    float2 o = *(const float2*)&acc_out[n * 64 + dl * 2];
    o.x += a0; o.y += a1;
    *(float2*)&acc_out[n * 64 + dl * 2] = o;
  } else {
    embb_out[n * 32 + dl] = pack2bf(a0, a1);
  }
}

extern "C" void kernel_launch(void* const* d_in, const int* in_sizes, int n_in,
                              void* d_out, int out_size, void* d_ws, size_t ws_size,
                              hipStream_t stream) {
  const int*   rows = (const int*)d_in[0];
  const int*   cols = (const int*)d_in[1];
  const float* vals = (const float*)d_in[2];
  const float* ue   = (const float*)d_in[3];
  const float* ie   = (const float*)d_in[4];
  const float* Wq   = (const float*)d_in[5];
  const float* Wk   = (const float*)d_in[6];
  const float* Wv   = (const float*)d_in[7];
  float* out = (float*)d_out;

  char* p = (char*)d_ws;
  auto alloc = [&](size_t b) { char* r = p; p += (b + 255) & ~(size_t)255; return (void*)r; };
  int*   cnt     = (int*)alloc((size_t)NTOT * 4);
  int*   row_ptr = (int*)alloc((size_t)(NTOT + 1) * 4);
  int*   cursor  = (int*)alloc((size_t)NTOT * 4);
  int*   bsums   = (int*)alloc(128 * 4);
  int*   boffs   = (int*)alloc(128 * 4);
  int*   ecols   = (int*)alloc((size_t)NEDGE * 4);
  float* evals   = (float*)alloc((size_t)NEDGE * 4);
  float*  Q     = (float*)alloc((size_t)NTOT * 64 * 4);
  uint32* KVb   = (uint32*)alloc((size_t)NTOT * 64 * 4);   // 256 B/node
  float*  embA  = (float*)alloc((size_t)NTOT * 64 * 4);
  float*  embB  = (float*)alloc((size_t)NTOT * 64 * 4);
  uint32* embbA = (uint32*)alloc((size_t)NTOT * 32 * 4);   // bf16 pairs
  uint32* embbB = (uint32*)alloc((size_t)NTOT * 32 * 4);

  hipMemsetAsync(cnt, 0, (size_t)NTOT * 4, stream);
  k_hist<<<(NEDGE + 255) / 256, 256, 0, stream>>>(rows, cnt);
  int nblk = (NTOT + 2047) / 2048;  // 74
  k_scan1<<<nblk, 256, 0, stream>>>(cnt, row_ptr, bsums);
  k_scan2<<<1, 128, 0, stream>>>(bsums, boffs, nblk);
  k_scan3<<<(NTOT + 255) / 256, 256, 0, stream>>>(row_ptr, boffs, cursor);
  k_fill<<<(NEDGE + 255) / 256, 256, 0, stream>>>(rows, cols, vals, cursor, ecols, evals);
  k_init<<<(NTOT * 16 + 255) / 256, 256, 0, stream>>>(ue, ie, embA, out);

  // GT layer 1: embA -> embB (fp32) + embbB (bf16, unused)
  k_qkv<<<(NTOT + 63) / 64, 256, 0, stream>>>(embA, Wq, Wk, Wv, Q, KVb);
  k_gt<<<(NTOT + 3) / 4, 256, 0, stream>>>(Q, KVb, row_ptr, ecols, embB, embbB, out);
  // GT layer 2: embB -> embA (fp32, unused) + embbA (bf16, feeds GCN1)
  k_qkv<<<(NTOT + 63) / 64, 256, 0, stream>>>(embB, Wq + 4096, Wk + 4096, Wv + 4096, Q, KVb);
  k_gt<<<(NTOT + 3) / 4, 256, 0, stream>>>(Q, KVb, row_ptr, ecols, embA, embbA, out);
  // GCN layers: bf16 in, bf16 out + acc
  k_gcn<<<(NTOT + 3) / 4, 256, 0, stream>>>(embbA, row_ptr, ecols, evals, embbB, out);
  k_gcn<<<(NTOT + 3) / 4, 256, 0, stream>>>(embbB, row_ptr, ecols, evals, embbA, out);
}

// Round 7
// 622.662 us; speedup vs baseline: 1.2262x; 1.2262x over previous
//
#include <hip/hip_runtime.h>

#define NUSERS 100000
#define NITEMS 50000
#define NTOT   150000
#define NEDGE  1000000

typedef unsigned int uint32;

__device__ __forceinline__ unsigned short f2bf(float f) {
  unsigned int u = __float_as_uint(f);
  u += 0x7FFFu + ((u >> 16) & 1u);   // round-to-nearest-even
  return (unsigned short)(u >> 16);
}
__device__ __forceinline__ uint32 pack2bf(float a, float b) {
  return (uint32)f2bf(a) | ((uint32)f2bf(b) << 16);
}
__device__ __forceinline__ float bf_lo(uint32 u) { return __uint_as_float(u << 16); }
__device__ __forceinline__ float bf_hi(uint32 u) { return __uint_as_float(u & 0xFFFF0000u); }

// ---- init: emb = concat(user, item); out = emb (embeds_lst[0]) ----
__global__ void k_init(const float* __restrict__ ue, const float* __restrict__ ie,
                       float* __restrict__ emb, float* __restrict__ out) {
  int i = blockIdx.x * 256 + threadIdx.x;  // float4 index
  if (i >= NTOT * 16) return;
  float4 v = (i < NUSERS * 16) ? ((const float4*)ue)[i]
                               : ((const float4*)ie)[i - NUSERS * 16];
  ((float4*)emb)[i] = v;
  ((float4*)out)[i] = v;
}

// ---- CSR build: histogram -> scan -> fill ----
__global__ void k_hist(const int* __restrict__ rows, int* __restrict__ cnt) {
  int e = blockIdx.x * 256 + threadIdx.x;
  if (e < NEDGE) atomicAdd(&cnt[rows[e]], 1);
}

__global__ void k_scan1(const int* __restrict__ cnt, int* __restrict__ partial,
                        int* __restrict__ blocksums) {
  __shared__ int s[256];
  int t = threadIdx.x, b = blockIdx.x;
  int base = b * 2048 + t * 8;
  int pre[8]; int sum = 0;
  #pragma unroll
  for (int j = 0; j < 8; ++j) {
    int idx = base + j;
    int x = (idx < NTOT) ? cnt[idx] : 0;
    pre[j] = sum; sum += x;
  }
  s[t] = sum; __syncthreads();
  for (int off = 1; off < 256; off <<= 1) {
    int x = (t >= off) ? s[t - off] : 0;
    __syncthreads(); s[t] += x; __syncthreads();
  }
  int excl = s[t] - sum;
  #pragma unroll
  for (int j = 0; j < 8; ++j) {
    int idx = base + j;
    if (idx < NTOT) partial[idx] = excl + pre[j];
  }
  if (t == 255) blocksums[b] = s[255];
}

__global__ void k_scan2(const int* __restrict__ blocksums, int* __restrict__ blockoffs, int nblk) {
  __shared__ int s[128];
  int t = threadIdx.x;
  int x = (t < nblk) ? blocksums[t] : 0;
  s[t] = x; __syncthreads();
  for (int off = 1; off < 128; off <<= 1) {
    int y = (t >= off) ? s[t - off] : 0;
    __syncthreads(); s[t] += y; __syncthreads();
  }
  if (t < nblk) blockoffs[t] = s[t] - x;
}

__global__ void k_scan3(int* __restrict__ row_ptr, const int* __restrict__ blockoffs,
                        int* __restrict__ cursor) {
  int i = blockIdx.x * 256 + threadIdx.x;
  if (i < NTOT) {
    int v = row_ptr[i] + blockoffs[i >> 11];
    row_ptr[i] = v; cursor[i] = v;
  }
  if (i == 0) row_ptr[NTOT] = NEDGE;
}

__global__ void k_fill(const int* __restrict__ rows, const int* __restrict__ cols,
                       const float* __restrict__ vals, int* __restrict__ cursor,
                       int* __restrict__ ecols, float* __restrict__ evals) {
  int e = blockIdx.x * 256 + threadIdx.x;
  if (e >= NEDGE) return;
  int r = rows[e];
  int pos = atomicAdd(&cursor[r], 1);
  ecols[pos] = cols[e];
  evals[pos] = vals[e];
}

// ---- QKV projection (R5 structure, bf16-packed weight LDS) ----
// Block = 256 = 4 waves; block handles 64 nodes (16 per wave).
// Weight LDS packed bf16: wqp[(k>>1)*64+lane] = (wq[k][lane], wq[k+1][lane]);
// wkp/wvp[k*32+m] = (w[k][2m], w[k][2m+1]). Total LDS: 24 KB weights +
// 17.4 KB emb tile = 41.4 KB -> 3 blocks/CU (was 65.5 KB -> 2).
// Q fp32 (lane = dim). K/V packed bf16 into KVb:
// lanes 0-31 own K dim-pairs (2m,2m+1); lanes 32-63 own V dim-pairs.
#define ESTRIDE 68
__global__ void __launch_bounds__(256) k_qkv(const float* __restrict__ emb,
    const float* __restrict__ Wq, const float* __restrict__ Wk, const float* __restrict__ Wv,
    float* __restrict__ Q, uint32* __restrict__ KVb) {
  __shared__ uint32 wqp[2048], wkp[2048], wvp[2048];
  __shared__ float es[64 * ESTRIDE];
  int t = threadIdx.x;
  #pragma unroll
  for (int r = 0; r < 8; ++r) {
    int j = t + r * 256;
    int k2 = j >> 6, l = j & 63;          // wq pair (2*k2, 2*k2+1) at lane l
    wqp[j] = pack2bf(Wq[k2 * 128 + l], Wq[k2 * 128 + 64 + l]);
    int k = j >> 5, m = j & 31;           // wk/wv dim pair (2m,2m+1) at row k
    float2 a = *(const float2*)&Wk[k * 64 + 2 * m];
    float2 b = *(const float2*)&Wv[k * 64 + 2 * m];
    wkp[j] = pack2bf(a.x, a.y);
    wvp[j] = pack2bf(b.x, b.y);
  }
  int n0 = blockIdx.x * 64;
  {
    int i = t >> 4, c = t & 15;  // node-row, float4 chunk
    #pragma unroll
    for (int r = 0; r < 4; ++r) {
      int li = i + r * 16;
      int node = n0 + li;
      float4 v = make_float4(0.f, 0.f, 0.f, 0.f);
      if (node < NTOT) v = ((const float4*)emb)[node * 16 + c];
      *(float4*)&es[li * ESTRIDE + c * 4] = v;
    }
  }
  __syncthreads();
  int wave = t >> 6, lane = t & 63;
  int half = lane >> 5;            // 0 -> K, 1 -> V
  int m = lane & 31;               // dim pair (2m, 2m+1)
  const uint32* wkvp = half ? wvp : wkp;
  float qa[16], kv0[16], kv1[16];
  #pragma unroll
  for (int u = 0; u < 16; ++u) { qa[u] = 0.f; kv0[u] = 0.f; kv1[u] = 0.f; }
  const float* eb = &es[(wave * 16) * ESTRIDE];
  for (int k0 = 0; k0 < 64; k0 += 4) {
    uint32 uq0 = wqp[(k0 >> 1) * 64 + lane];
    uint32 uq1 = wqp[(k0 >> 1) * 64 + 64 + lane];
    float q0 = bf_lo(uq0), q1 = bf_hi(uq0);
    float q2 = bf_lo(uq1), q3 = bf_hi(uq1);
    uint32 uw0 = wkvp[(k0 + 0) * 32 + m];
    uint32 uw1 = wkvp[(k0 + 1) * 32 + m];
    uint32 uw2 = wkvp[(k0 + 2) * 32 + m];
    uint32 uw3 = wkvp[(k0 + 3) * 32 + m];
    float w0x = bf_lo(uw0), w0y = bf_hi(uw0);
    float w1x = bf_lo(uw1), w1y = bf_hi(uw1);
    float w2x = bf_lo(uw2), w2y = bf_hi(uw2);
    float w3x = bf_lo(uw3), w3y = bf_hi(uw3);
    #pragma unroll
    for (int u = 0; u < 16; ++u) {
      float4 e4 = *(const float4*)&eb[u * ESTRIDE + k0];  // broadcast
      qa[u] = fmaf(e4.x, q0, qa[u]);
      qa[u] = fmaf(e4.y, q1, qa[u]);
      qa[u] = fmaf(e4.z, q2, qa[u]);
      qa[u] = fmaf(e4.w, q3, qa[u]);
      kv0[u] = fmaf(e4.x, w0x, kv0[u]);
      kv0[u] = fmaf(e4.y, w1x, kv0[u]);
      kv0[u] = fmaf(e4.z, w2x, kv0[u]);
      kv0[u] = fmaf(e4.w, w3x, kv0[u]);
      kv1[u] = fmaf(e4.x, w0y, kv1[u]);
      kv1[u] = fmaf(e4.y, w1y, kv1[u]);
      kv1[u] = fmaf(e4.z, w2y, kv1[u]);
      kv1[u] = fmaf(e4.w, w3y, kv1[u]);
    }
  }
  int uidx = (m >> 1) * 4 + half * 2 + (m & 1);
  #pragma unroll
  for (int u = 0; u < 16; ++u) {
    int n = n0 + wave * 16 + u;
    if (n < NTOT) {
      Q[n * 64 + lane] = qa[u];
      KVb[n * 64 + uidx] = pack2bf(kv0[u], kv1[u]);
    }
  }
}

// ---- GT layer: wave = node; 4 edge-slots x 16 lanes; one dwordx4/edge ----
__global__ void __launch_bounds__(256) k_gt(const float* __restrict__ Q,
    const uint32* __restrict__ KVb, const int* __restrict__ row_ptr,
    const int* __restrict__ ecols, float* __restrict__ emb_out, float* __restrict__ acc_out) {
  int t = threadIdx.x;
  int n = blockIdx.x * 4 + (t >> 6);
  if (n >= NTOT) return;
  int lane = t & 63;
  int es = lane >> 4;
  int dl = lane & 15;
  float4 q4 = *(const float4*)&Q[n * 64 + dl * 4];
  int s     = __builtin_amdgcn_readfirstlane(row_ptr[n]);
  int e_end = __builtin_amdgcn_readfirstlane(row_ptr[n + 1]);
  float den = 0.f;
  float4 acc = make_float4(0.f, 0.f, 0.f, 0.f);
  #pragma unroll 2
  for (int p = s; p < e_end; p += 4) {
    int idx = p + es;
    float ex = 0.f;
    float4 v4 = make_float4(0.f, 0.f, 0.f, 0.f);
    if (idx < e_end) {
      int c = ecols[idx];
      uint4 w = *(const uint4*)&KVb[c * 64 + dl * 4];
      float kx = bf_lo(w.x), ky = bf_hi(w.x);
      float kz = bf_lo(w.y), kw = bf_hi(w.y);
      v4.x = bf_lo(w.z); v4.y = bf_hi(w.z);
      v4.z = bf_lo(w.w); v4.w = bf_hi(w.w);
      float x = q4.x * kx + q4.y * ky + q4.z * kz + q4.w * kw;
      x += __shfl_xor(x, 1);
      x += __shfl_xor(x, 2);
      x = fminf(fmaxf(x, -10.f), 10.f);
      ex = __expf(x);
    }
    den += ex;
    acc.x = fmaf(ex, v4.x, acc.x);
    acc.y = fmaf(ex, v4.y, acc.y);
    acc.z = fmaf(ex, v4.z, acc.z);
    acc.w = fmaf(ex, v4.w, acc.w);
  }
  // reduce across the 4 edge slots
  #pragma unroll
  for (int off = 16; off <= 32; off <<= 1) {
    den  += __shfl_xor(den, off);
    acc.x += __shfl_xor(acc.x, off);
    acc.y += __shfl_xor(acc.y, off);
    acc.z += __shfl_xor(acc.z, off);
    acc.w += __shfl_xor(acc.w, off);
  }
  float inv = 1.f / (den + 1e-8f);
  float4 r = make_float4(acc.x * inv, acc.y * inv, acc.z * inv, acc.w * inv);
  if (es == 0) {
    *(float4*)&emb_out[n * 64 + dl * 4] = r;
  } else if (es == 1) {
    float4 o = *(const float4*)&acc_out[n * 64 + dl * 4];
    o.x += r.x; o.y += r.y; o.z += r.z; o.w += r.w;
    *(float4*)&acc_out[n * 64 + dl * 4] = o;
  }
}

// ---- GCN layer (spmm): wave per node, lane = dim, 4x unrolled ----
__global__ void __launch_bounds__(256) k_gcn(const float* __restrict__ emb,
    const int* __restrict__ row_ptr, const int* __restrict__ ecols, const float* __restrict__ evals,
    float* __restrict__ emb_out, float* __restrict__ acc_out) {
  int t = threadIdx.x;
  int n = blockIdx.x * 4 + (t >> 6);
  if (n >= NTOT) return;
  int lane = t & 63;
  int s     = __builtin_amdgcn_readfirstlane(row_ptr[n]);
  int e_end = __builtin_amdgcn_readfirstlane(row_ptr[n + 1]);
  float a0 = 0.f, a1 = 0.f, a2 = 0.f, a3 = 0.f;
  int p = s;
  for (; p + 4 <= e_end; p += 4) {
    int c0 = ecols[p], c1 = ecols[p + 1], c2 = ecols[p + 2], c3 = ecols[p + 3];
    float w0 = evals[p], w1 = evals[p + 1], w2 = evals[p + 2], w3 = evals[p + 3];
    float m0 = emb[c0 * 64 + lane];
    float m1 = emb[c1 * 64 + lane];
    float m2 = emb[c2 * 64 + lane];
    float m3 = emb[c3 * 64 + lane];
    a0 = fmaf(w0, m0, a0);
    a1 = fmaf(w1, m1, a1);
    a2 = fmaf(w2, m2, a2);
    a3 = fmaf(w3, m3, a3);
  }
  for (; p < e_end; ++p) {
    int c = ecols[p];
    a0 = fmaf(evals[p], emb[c * 64 + lane], a0);
  }
  float acc = (a0 + a1) + (a2 + a3);
  emb_out[n * 64 + lane] = acc;
  acc_out[n * 64 + lane] += acc;
}

extern "C" void kernel_launch(void* const* d_in, const int* in_sizes, int n_in,
                              void* d_out, int out_size, void* d_ws, size_t ws_size,
                              hipStream_t stream) {
  const int*   rows = (const int*)d_in[0];
  const int*   cols = (const int*)d_in[1];
  const float* vals = (const float*)d_in[2];
  const float* ue   = (const float*)d_in[3];
  const float* ie   = (const float*)d_in[4];
  const float* Wq   = (const float*)d_in[5];
  const float* Wk   = (const float*)d_in[6];
  const float* Wv   = (const float*)d_in[7];
  float* out = (float*)d_out;

  char* p = (char*)d_ws;
  auto alloc = [&](size_t b) { char* r = p; p += (b + 255) & ~(size_t)255; return (void*)r; };
  int*   cnt     = (int*)alloc((size_t)NTOT * 4);
  int*   row_ptr = (int*)alloc((size_t)(NTOT + 1) * 4);
  int*   cursor  = (int*)alloc((size_t)NTOT * 4);
  int*   bsums   = (int*)alloc(128 * 4);
  int*   boffs   = (int*)alloc(128 * 4);
  int*   ecols   = (int*)alloc((size_t)NEDGE * 4);
  float* evals   = (float*)alloc((size_t)NEDGE * 4);
  float*  Q   = (float*)alloc((size_t)NTOT * 64 * 4);
  uint32* KVb = (uint32*)alloc((size_t)NTOT * 64 * 4);  // 64 uints/node = 256 B
  float* embA = (float*)alloc((size_t)NTOT * 64 * 4);
  float* embB = (float*)alloc((size_t)NTOT * 64 * 4);

  hipMemsetAsync(cnt, 0, (size_t)NTOT * 4, stream);
  k_hist<<<(NEDGE + 255) / 256, 256, 0, stream>>>(rows, cnt);
  int nblk = (NTOT + 2047) / 2048;  // 74
  k_scan1<<<nblk, 256, 0, stream>>>(cnt, row_ptr, bsums);
  k_scan2<<<1, 128, 0, stream>>>(bsums, boffs, nblk);
  k_scan3<<<(NTOT + 255) / 256, 256, 0, stream>>>(row_ptr, boffs, cursor);
  k_fill<<<(NEDGE + 255) / 256, 256, 0, stream>>>(rows, cols, vals, cursor, ecols, evals);
  k_init<<<(NTOT * 16 + 255) / 256, 256, 0, stream>>>(ue, ie, embA, out);

  float* cur = embA;
  float* nxt = embB;
  for (int l = 0; l < 2; ++l) {
    k_qkv<<<(NTOT + 63) / 64, 256, 0, stream>>>(cur, Wq + l * 4096, Wk + l * 4096, Wv + l * 4096,
                                                Q, KVb);
    k_gt<<<(NTOT + 3) / 4, 256, 0, stream>>>(Q, KVb, row_ptr, ecols, nxt, out);
    float* tmp = cur; cur = nxt; nxt = tmp;
  }
  for (int l = 0; l < 2; ++l) {
    k_gcn<<<(NTOT + 3) / 4, 256, 0, stream>>>(cur, row_ptr, ecols, evals, nxt, out);
    float* tmp = cur; cur = nxt; nxt = tmp;
  }
}

// Round 8
// 556.034 us; speedup vs baseline: 1.3731x; 1.1198x over previous
//
#include <hip/hip_runtime.h>

#define NUSERS 100000
#define NITEMS 50000
#define NTOT   150000
#define NEDGE  1000000
#define NTILE  9375   // NTOT / 16

typedef unsigned int uint32;
typedef __attribute__((ext_vector_type(8))) short short8;
typedef __attribute__((ext_vector_type(4))) float f32x4;

__device__ __forceinline__ unsigned short f2bf(float f) {
  unsigned int u = __float_as_uint(f);
  u += 0x7FFFu + ((u >> 16) & 1u);   // round-to-nearest-even
  return (unsigned short)(u >> 16);
}
__device__ __forceinline__ uint32 pack2bf(float a, float b) {
  return (uint32)f2bf(a) | ((uint32)f2bf(b) << 16);
}
__device__ __forceinline__ float bf_lo(uint32 u) { return __uint_as_float(u << 16); }
__device__ __forceinline__ float bf_hi(uint32 u) { return __uint_as_float(u & 0xFFFF0000u); }

// ---- init: out = concat(user,item); embb0 = bf16-pair packed copy ----
__global__ void k_init(const float* __restrict__ ue, const float* __restrict__ ie,
                       uint32* __restrict__ embb, float* __restrict__ out) {
  int i = blockIdx.x * 256 + threadIdx.x;  // float4 index
  if (i >= NTOT * 16) return;
  float4 v = (i < NUSERS * 16) ? ((const float4*)ue)[i]
                               : ((const float4*)ie)[i - NUSERS * 16];
  ((float4*)out)[i] = v;
  uint2 pk;
  pk.x = pack2bf(v.x, v.y);
  pk.y = pack2bf(v.z, v.w);
  ((uint2*)embb)[i] = pk;
}

// ---- W pack: Wbg[l*6144 + mat*2048 + n*32 + k2] = bf16(W[2k2][n], W[2k2+1][n]) ----
__global__ void k_wpack(const float* __restrict__ Wq, const float* __restrict__ Wk,
                        const float* __restrict__ Wv, uint32* __restrict__ Wbg) {
  int t = blockIdx.x * 256 + threadIdx.x;
  if (t >= 12288) return;
  int l = t / 6144, rem = t % 6144, mat = rem / 2048, j = rem % 2048;
  int n = j >> 5, k2 = j & 31;
  const float* W = (mat == 0 ? Wq : mat == 1 ? Wk : Wv) + l * 4096;
  Wbg[t] = pack2bf(W[k2 * 128 + n], W[k2 * 128 + 64 + n]);
}

// ---- CSR build: histogram -> scan -> fill ----
__global__ void k_hist(const int* __restrict__ rows, int* __restrict__ cnt) {
  int e = blockIdx.x * 256 + threadIdx.x;
  if (e < NEDGE) atomicAdd(&cnt[rows[e]], 1);
}

__global__ void k_scan1(const int* __restrict__ cnt, int* __restrict__ partial,
                        int* __restrict__ blocksums) {
  __shared__ int s[256];
  int t = threadIdx.x, b = blockIdx.x;
  int base = b * 2048 + t * 8;
  int pre[8]; int sum = 0;
  #pragma unroll
  for (int j = 0; j < 8; ++j) {
    int idx = base + j;
    int x = (idx < NTOT) ? cnt[idx] : 0;
    pre[j] = sum; sum += x;
  }
  s[t] = sum; __syncthreads();
  for (int off = 1; off < 256; off <<= 1) {
    int x = (t >= off) ? s[t - off] : 0;
    __syncthreads(); s[t] += x; __syncthreads();
  }
  int excl = s[t] - sum;
  #pragma unroll
  for (int j = 0; j < 8; ++j) {
    int idx = base + j;
    if (idx < NTOT) partial[idx] = excl + pre[j];
  }
  if (t == 255) blocksums[b] = s[255];
}

__global__ void k_scan2(const int* __restrict__ blocksums, int* __restrict__ blockoffs, int nblk) {
  __shared__ int s[128];
  int t = threadIdx.x;
  int x = (t < nblk) ? blocksums[t] : 0;
  s[t] = x; __syncthreads();
  for (int off = 1; off < 128; off <<= 1) {
    int y = (t >= off) ? s[t - off] : 0;
    __syncthreads(); s[t] += y; __syncthreads();
  }
  if (t < nblk) blockoffs[t] = s[t] - x;
}

__global__ void k_scan3(int* __restrict__ row_ptr, const int* __restrict__ blockoffs,
                        int* __restrict__ cursor) {
  int i = blockIdx.x * 256 + threadIdx.x;
  if (i < NTOT) {
    int v = row_ptr[i] + blockoffs[i >> 11];
    row_ptr[i] = v; cursor[i] = v;
  }
  if (i == 0) row_ptr[NTOT] = NEDGE;
}

__global__ void k_fill(const int* __restrict__ rows, const int* __restrict__ cols,
                       const float* __restrict__ vals, int* __restrict__ cursor,
                       int* __restrict__ ecols, float* __restrict__ evals) {
  int e = blockIdx.x * 256 + threadIdx.x;
  if (e >= NEDGE) return;
  int r = rows[e];
  int pos = atomicAdd(&cursor[r], 1);
  ecols[pos] = cols[e];
  evals[pos] = vals[e];
}

// ---- QKV v5: MFMA. wave = 16-node tile. No LDS in main loop. ----
// A-frag (16x16x32 bf16): lane L holds A[node = L&15][k = (L>>4)*8 + j].
// B-frag: lane L holds B[k = (L>>4)*8 + j][n = L&15], from Wbg [n*32+k2] pairs.
// C/D:   lane L holds D[node = (L>>4)*4 + reg][col = L&15] (per 16-col tile).
// Epilogue transposes via wave-local LDS scratch; Q fp32 [n][64] and KVb
// layouts identical to R7 so k_gt is unchanged.
__global__ void __launch_bounds__(256) k_qkv(const uint32* __restrict__ embb,
    const uint32* __restrict__ Wbg, float* __restrict__ Q, uint32* __restrict__ KVb) {
  __shared__ float scr[4][2][16][68];  // [wave][K/V][node][dim(+pad)] = 34816 B
  int t = threadIdx.x;
  int wave = t >> 6, lane = t & 63;
  int tile = blockIdx.x * 4 + wave;
  if (tile >= NTILE) return;
  int c = lane & 15, quad = lane >> 4;
  int nodeBase = tile * 16;
  const uint32* arow = embb + (nodeBase + c) * 32 + quad * 4;
  uint4 a0u = *(const uint4*)arow;          // dims quad*8 .. +7
  uint4 a1u = *(const uint4*)(arow + 16);   // dims 32+quad*8 .. +7
  short8 a0 = *(short8*)&a0u;
  short8 a1 = *(short8*)&a1u;
  float (*SK)[68] = scr[wave][0];
  float (*SV)[68] = scr[wave][1];
  const uint32* wbase = Wbg + c * 32 + quad * 4;
  #pragma unroll
  for (int mat = 0; mat < 3; ++mat) {
    f32x4 acc[4];
    #pragma unroll
    for (int nt = 0; nt < 4; ++nt) acc[nt] = (f32x4){0.f, 0.f, 0.f, 0.f};
    const uint32* wb = wbase + mat * 2048;
    #pragma unroll
    for (int nt = 0; nt < 4; ++nt) {
      uint4 b0u = *(const uint4*)(wb + nt * 512);        // kh=0
      uint4 b1u = *(const uint4*)(wb + nt * 512 + 16);   // kh=1
      short8 b0 = *(short8*)&b0u;
      short8 b1 = *(short8*)&b1u;
      acc[nt] = __builtin_amdgcn_mfma_f32_16x16x32_bf16(a0, b0, acc[nt], 0, 0, 0);
      acc[nt] = __builtin_amdgcn_mfma_f32_16x16x32_bf16(a1, b1, acc[nt], 0, 0, 0);
    }
    float (*S)[68] = (mat == 2) ? SV : SK;   // Q and K reuse SK
    #pragma unroll
    for (int nt = 0; nt < 4; ++nt)
      #pragma unroll
      for (int r = 0; r < 4; ++r)
        S[quad * 4 + r][nt * 16 + c] = acc[nt][r];
    if (mat == 0) {
      #pragma unroll
      for (int i = 0; i < 4; ++i) {
        int node = i * 4 + quad;
        f32x4 q4 = *(f32x4*)&SK[node][c * 4];
        *(f32x4*)&Q[(nodeBase + node) * 64 + c * 4] = q4;
      }
    } else if (mat == 2) {
      #pragma unroll
      for (int i = 0; i < 4; ++i) {
        int node = i * 4 + quad;
        f32x4 K4 = *(f32x4*)&SK[node][c * 4];
        f32x4 V4 = *(f32x4*)&SV[node][c * 4];
        uint4 o;
        o.x = pack2bf(K4[0], K4[1]);
        o.y = pack2bf(K4[2], K4[3]);
        o.z = pack2bf(V4[0], V4[1]);
        o.w = pack2bf(V4[2], V4[3]);
        *(uint4*)&KVb[(nodeBase + node) * 64 + c * 4] = o;
      }
    }
  }
}

// ---- GT layer: wave = node; 4 edge-slots x 16 lanes; one dwordx4/edge ----
__global__ void __launch_bounds__(256) k_gt(const float* __restrict__ Q,
    const uint32* __restrict__ KVb, const int* __restrict__ row_ptr,
    const int* __restrict__ ecols, float* __restrict__ emb_out,
    uint32* __restrict__ embb_out, float* __restrict__ acc_out) {
  int t = threadIdx.x;
  int n = blockIdx.x * 4 + (t >> 6);
  if (n >= NTOT) return;
  int lane = t & 63;
  int es = lane >> 4;
  int dl = lane & 15;
  float4 q4 = *(const float4*)&Q[n * 64 + dl * 4];
  int s     = __builtin_amdgcn_readfirstlane(row_ptr[n]);
  int e_end = __builtin_amdgcn_readfirstlane(row_ptr[n + 1]);
  float den = 0.f;
  float4 acc = make_float4(0.f, 0.f, 0.f, 0.f);
  #pragma unroll 2
  for (int p = s; p < e_end; p += 4) {
    int idx = p + es;
    float ex = 0.f;
    float4 v4 = make_float4(0.f, 0.f, 0.f, 0.f);
    if (idx < e_end) {
      int cc = ecols[idx];
      uint4 w = *(const uint4*)&KVb[cc * 64 + dl * 4];
      float kx = bf_lo(w.x), ky = bf_hi(w.x);
      float kz = bf_lo(w.y), kw = bf_hi(w.y);
      v4.x = bf_lo(w.z); v4.y = bf_hi(w.z);
      v4.z = bf_lo(w.w); v4.w = bf_hi(w.w);
      float x = q4.x * kx + q4.y * ky + q4.z * kz + q4.w * kw;
      x += __shfl_xor(x, 1);
      x += __shfl_xor(x, 2);
      x = fminf(fmaxf(x, -10.f), 10.f);
      ex = __expf(x);
    }
    den += ex;
    acc.x = fmaf(ex, v4.x, acc.x);
    acc.y = fmaf(ex, v4.y, acc.y);
    acc.z = fmaf(ex, v4.z, acc.z);
    acc.w = fmaf(ex, v4.w, acc.w);
  }
  #pragma unroll
  for (int off = 16; off <= 32; off <<= 1) {
    den  += __shfl_xor(den, off);
    acc.x += __shfl_xor(acc.x, off);
    acc.y += __shfl_xor(acc.y, off);
    acc.z += __shfl_xor(acc.z, off);
    acc.w += __shfl_xor(acc.w, off);
  }
  float inv = 1.f / (den + 1e-8f);
  float4 r = make_float4(acc.x * inv, acc.y * inv, acc.z * inv, acc.w * inv);
  if (es == 0) {
    *(float4*)&emb_out[n * 64 + dl * 4] = r;
  } else if (es == 1) {
    float4 o = *(const float4*)&acc_out[n * 64 + dl * 4];
    o.x += r.x; o.y += r.y; o.z += r.z; o.w += r.w;
    *(float4*)&acc_out[n * 64 + dl * 4] = o;
  } else if (es == 2) {
    uint2 pk;
    pk.x = pack2bf(r.x, r.y);
    pk.y = pack2bf(r.z, r.w);
    *(uint2*)&embb_out[n * 32 + dl * 2] = pk;
  }
}

// ---- GCN layer (spmm): wave per node, lane = dim, 4x unrolled (fp32) ----
__global__ void __launch_bounds__(256) k_gcn(const float* __restrict__ emb,
    const int* __restrict__ row_ptr, const int* __restrict__ ecols, const float* __restrict__ evals,
    float* __restrict__ emb_out, float* __restrict__ acc_out) {
  int t = threadIdx.x;
  int n = blockIdx.x * 4 + (t >> 6);
  if (n >= NTOT) return;
  int lane = t & 63;
  int s     = __builtin_amdgcn_readfirstlane(row_ptr[n]);
  int e_end = __builtin_amdgcn_readfirstlane(row_ptr[n + 1]);
  float a0 = 0.f, a1 = 0.f, a2 = 0.f, a3 = 0.f;
  int p = s;
  for (; p + 4 <= e_end; p += 4) {
    int c0 = ecols[p], c1 = ecols[p + 1], c2 = ecols[p + 2], c3 = ecols[p + 3];
    float w0 = evals[p], w1 = evals[p + 1], w2 = evals[p + 2], w3 = evals[p + 3];
    float m0 = emb[c0 * 64 + lane];
    float m1 = emb[c1 * 64 + lane];
    float m2 = emb[c2 * 64 + lane];
    float m3 = emb[c3 * 64 + lane];
    a0 = fmaf(w0, m0, a0);
    a1 = fmaf(w1, m1, a1);
    a2 = fmaf(w2, m2, a2);
    a3 = fmaf(w3, m3, a3);
  }
  for (; p < e_end; ++p) {
    int c = ecols[p];
    a0 = fmaf(evals[p], emb[c * 64 + lane], a0);
  }
  float acc = (a0 + a1) + (a2 + a3);
  emb_out[n * 64 + lane] = acc;
  acc_out[n * 64 + lane] += acc;
}

extern "C" void kernel_launch(void* const* d_in, const int* in_sizes, int n_in,
                              void* d_out, int out_size, void* d_ws, size_t ws_size,
                              hipStream_t stream) {
  const int*   rows = (const int*)d_in[0];
  const int*   cols = (const int*)d_in[1];
  const float* vals = (const float*)d_in[2];
  const float* ue   = (const float*)d_in[3];
  const float* ie   = (const float*)d_in[4];
  const float* Wq   = (const float*)d_in[5];
  const float* Wk   = (const float*)d_in[6];
  const float* Wv   = (const float*)d_in[7];
  float* out = (float*)d_out;

  char* p = (char*)d_ws;
  auto alloc = [&](size_t b) { char* r = p; p += (b + 255) & ~(size_t)255; return (void*)r; };
  int*   cnt     = (int*)alloc((size_t)NTOT * 4);
  int*   row_ptr = (int*)alloc((size_t)(NTOT + 1) * 4);
  int*   cursor  = (int*)alloc((size_t)NTOT * 4);
  int*   bsums   = (int*)alloc(128 * 4);
  int*   boffs   = (int*)alloc(128 * 4);
  int*   ecols   = (int*)alloc((size_t)NEDGE * 4);
  float* evals   = (float*)alloc((size_t)NEDGE * 4);
  uint32* Wbg  = (uint32*)alloc((size_t)12288 * 4);
  float*  Q    = (float*)alloc((size_t)NTOT * 64 * 4);
  uint32* KVb  = (uint32*)alloc((size_t)NTOT * 64 * 4);   // 256 B/node
  float*  embA = (float*)alloc((size_t)NTOT * 64 * 4);
  float*  embB = (float*)alloc((size_t)NTOT * 64 * 4);
  uint32* embb0 = (uint32*)alloc((size_t)NTOT * 32 * 4);  // bf16 pairs
  uint32* embb1 = (uint32*)alloc((size_t)NTOT * 32 * 4);

  hipMemsetAsync(cnt, 0, (size_t)NTOT * 4, stream);
  k_hist<<<(NEDGE + 255) / 256, 256, 0, stream>>>(rows, cnt);
  int nblk = (NTOT + 2047) / 2048;  // 74
  k_scan1<<<nblk, 256, 0, stream>>>(cnt, row_ptr, bsums);
  k_scan2<<<1, 128, 0, stream>>>(bsums, boffs, nblk);
  k_scan3<<<(NTOT + 255) / 256, 256, 0, stream>>>(row_ptr, boffs, cursor);
  k_fill<<<(NEDGE + 255) / 256, 256, 0, stream>>>(rows, cols, vals, cursor, ecols, evals);
  k_wpack<<<48, 256, 0, stream>>>(Wq, Wk, Wv, Wbg);
  k_init<<<(NTOT * 16 + 255) / 256, 256, 0, stream>>>(ue, ie, embb0, out);

  // GT layer 1
  k_qkv<<<(NTILE + 3) / 4, 256, 0, stream>>>(embb0, Wbg, Q, KVb);
  k_gt<<<(NTOT + 3) / 4, 256, 0, stream>>>(Q, KVb, row_ptr, ecols, embA, embb1, out);
  // GT layer 2
  k_qkv<<<(NTILE + 3) / 4, 256, 0, stream>>>(embb1, Wbg + 6144, Q, KVb);
  k_gt<<<(NTOT + 3) / 4, 256, 0, stream>>>(Q, KVb, row_ptr, ecols, embB, embb0, out);
  // GCN layers (fp32 chain from GT2's fp32 output)
  k_gcn<<<(NTOT + 3) / 4, 256, 0, stream>>>(embB, row_ptr, ecols, evals, embA, out);
  k_gcn<<<(NTOT + 3) / 4, 256, 0, stream>>>(embA, row_ptr, ecols, evals, embB, out);
}